// Round 21
// baseline (58.376 us; speedup 1.0000x reference)
//
#include <hip/hip_runtime.h>

// AdaPT_Linear: per-tensor int8 quantized linear.
// out = (qx @ qw^T).f32 / (sa*sw) + qb.f32/sb
// x: [16384,1024] f32, w: [1024,1024] f32, b: [1024] f32, out: [16384,1024] f32

#define M_ROWS 16384
#define K_DIM  1024
#define N_OUT  1024

typedef int v4i __attribute__((ext_vector_type(4)));
typedef float v4f __attribute__((ext_vector_type(4)));

__device__ __forceinline__ void gload_lds16(const void* g, void* l) {
  __builtin_amdgcn_global_load_lds(
      (const __attribute__((address_space(1))) void*)g,
      (__attribute__((address_space(3))) void*)l, 16, 0, 0);
}

__device__ __forceinline__ float block_reduce_max4(float m, float* red) {
#pragma unroll
  for (int off = 32; off > 0; off >>= 1)
    m = fmaxf(m, __shfl_down(m, off));
  const int wid = threadIdx.x >> 6, lane = threadIdx.x & 63;
  if (lane == 0) red[wid] = m;
  __syncthreads();
  float r = fmaxf(fmaxf(red[0], red[1]), fmaxf(red[2], red[3]));
  __syncthreads();
  return r;
}

// K1: blocks [0,2048) reduce x -> px, blocks [2048,2304) reduce w -> pw
__global__ void amax_both(const float* __restrict__ x, const float* __restrict__ wsrc,
                          float* __restrict__ px, float* __restrict__ pw) {
  __shared__ float red[4];
  const bool isx = blockIdx.x < 2048;
  const float* src = isx ? x : wsrc;
  const int n4   = isx ? (M_ROWS * K_DIM / 4) : (N_OUT * K_DIM / 4);
  const int nblk = isx ? 2048 : 256;
  const int bidl = isx ? blockIdx.x : blockIdx.x - 2048;
  float m = 0.0f;
  const int stride = nblk * 256;
  for (int idx = bidl * 256 + threadIdx.x; idx < n4; idx += stride) {
    float4 v = ((const float4*)src)[idx];
    m = fmaxf(m, fmaxf(fmaxf(fabsf(v.x), fabsf(v.y)), fmaxf(fabsf(v.z), fabsf(v.w))));
  }
  float r = block_reduce_max4(m, red);
  if (threadIdx.x == 0) (isx ? px : pw)[bidl] = r;
}

// K2: finalize folded into quant — EVERY block redundantly reduces the 2304
// partials (deterministic identical order -> bit-identical scales), then
// quantizes its slice. Block 2304 computes bias amax + bdeq + amax[].
__global__ void quant_fin(const float* __restrict__ x, const float* __restrict__ wsrc,
                          const float* __restrict__ bias,
                          signed char* __restrict__ qx, signed char* __restrict__ qw,
                          const float* __restrict__ px, const float* __restrict__ pw,
                          float* __restrict__ amax, float* __restrict__ bdeq) {
  __shared__ float red[4];
  const int tid = threadIdx.x;

  // local finalize (partials are >= 0; px: 512 float4, pw: 64 float4)
  float m = 0.0f;
#pragma unroll
  for (int i = 0; i < 2; ++i) {
    float4 v = ((const float4*)px)[tid + i * 256];
    m = fmaxf(m, fmaxf(fmaxf(v.x, v.y), fmaxf(v.z, v.w)));
  }
  float rx = block_reduce_max4(m, red);
  m = 0.0f;
  if (tid < 64) {
    float4 v = ((const float4*)pw)[tid];
    m = fmaxf(fmaxf(v.x, v.y), fmaxf(v.z, v.w));
  }
  float rw = block_reduce_max4(m, red);
  if (rx == 0.0f) rx = 1.0f;
  if (rw == 0.0f) rw = 1.0f;

  if (blockIdx.x == 2304) {  // bias block: amax[] + dequantized bias
    float4 bv = ((const float4*)bias)[tid];  // 256*4 == 1024
    m = fmaxf(fmaxf(fabsf(bv.x), fabsf(bv.y)), fmaxf(fabsf(bv.z), fabsf(bv.w)));
    float rb = block_reduce_max4(m, red);
    if (rb == 0.0f) rb = 1.0f;
    if (tid == 0) { amax[0] = rx; amax[1] = rw; amax[2] = rb; }
    const float sb = 127.0f / rb;
    float4 q;
    q.x = fminf(fmaxf(rintf(sb * bv.x), -127.0f), 127.0f) / sb;
    q.y = fminf(fmaxf(rintf(sb * bv.y), -127.0f), 127.0f) / sb;
    q.z = fminf(fmaxf(rintf(sb * bv.z), -127.0f), 127.0f) / sb;
    q.w = fminf(fmaxf(rintf(sb * bv.w), -127.0f), 127.0f) / sb;
    ((float4*)bdeq)[tid] = q;
    return;
  }

  const bool isx = blockIdx.x < 2048;
  const float* src = isx ? x : wsrc;
  signed char* dst = isx ? qx : qw;
  const int n4   = isx ? (M_ROWS * K_DIM / 4) : (N_OUT * K_DIM / 4);
  const int nblk = isx ? 2048 : 256;
  const int bidl = isx ? blockIdx.x : blockIdx.x - 2048;
  const float s = 127.0f / (isx ? rx : rw);
  const int stride = nblk * 256;
  for (int idx = bidl * 256 + tid; idx < n4; idx += stride) {
    float4 v = ((const float4*)src)[idx];
    int q0 = (int)fminf(fmaxf(rintf(s * v.x), -127.0f), 127.0f);
    int q1 = (int)fminf(fmaxf(rintf(s * v.y), -127.0f), 127.0f);
    int q2 = (int)fminf(fmaxf(rintf(s * v.z), -127.0f), 127.0f);
    int q3 = (int)fminf(fmaxf(rintf(s * v.w), -127.0f), 127.0f);
    unsigned int packed = (q0 & 0xff) | ((q1 & 0xff) << 8) |
                          ((q2 & 0xff) << 16) | ((q3 & 0xff) << 24);
    ((unsigned int*)dst)[idx] = packed;
  }
}

// ---------------------------------------------------------------------------
// i8 GEMM — R20 verbatim EXCEPT the epilogue stores are PLAIN cached stores
// (was __builtin_nontemporal_store). A/B theory: fills hit 6.7TB/s with
// plain stores (L2 write-back aggregates full lines, drains async); our nt
// stores measured ~2TB/s effective — nt may bypass L2 aggregation on gfx950.
// Same bytes, different path. Everything else proven: 128x128 tile, BK=64,
// 8 waves, triple-buffered 48KB LDS, single-barrier K-loop, XOR swizzle,
// block-cooperative wide-segment (512B) store epilogue.
// ---------------------------------------------------------------------------
#define NKT 16

__global__ __launch_bounds__(512, 4) void gemm_kernel(
    const signed char* __restrict__ qx, const signed char* __restrict__ qw,
    const float* __restrict__ amax, const float* __restrict__ bdeq,
    float* __restrict__ out) {
  __shared__ char lds[49152];  // 3 bufs x 16KB (A 8K + B 8K)

  const int tid  = threadIdx.x;
  const int w    = tid >> 6;
  const int lane = tid & 63;
  const int wm = w >> 2;   // 0..1 (64 rows)
  const int wn = w & 3;    // 0..3 (32 cols)
  const int fr = lane & 15;
  const int q  = lane >> 4;

  // XCD-aware swizzle (grid 1024 = 8 XCDs x 128 contiguous)
  const int bid = blockIdx.x;
  const int wg  = (bid & 7) * 128 + (bid >> 3);
  const int Mbase = (wg >> 3) * 128;
  const int Nbase = (wg & 7) * 128;

  const signed char* gA = qx + (size_t)Mbase * K_DIM;
  const signed char* gB = qw + (size_t)Nbase * K_DIM;

  const int scol = ((tid & 3) ^ ((tid >> 3) & 3)) << 4;
  const size_t srowK = (size_t)(tid >> 2) * K_DIM;
  const int u0 = (q ^ ((fr >> 1) & 3)) << 4;

  const float inv_denom = (amax[0] * amax[1]) * (1.0f / 16129.0f);

  v4i acc[4][2] = {};
  v4i Ar[4], Br[2];

#define STG(BASE, T)                                                           \
  do {                                                                         \
    const int _k0 = (T)*64 + scol;                                             \
    gload_lds16(gA + srowK + _k0, (BASE) + tid * 16);                          \
    gload_lds16(gB + srowK + _k0, (BASE) + 8192 + tid * 16);                   \
  } while (0)

#define VM(N) asm volatile("s_waitcnt vmcnt(" #N ")" ::: "memory")

  char* pR = lds;
  char* pS = lds + 16384;
  char* pF = lds + 32768;

  STG(pR, 0);

#pragma unroll
  for (int kt = 0; kt < NKT; ++kt) {
    if (kt + 1 < NKT) {
      STG(pS, kt + 1);
      VM(2);
    } else {
      VM(0);
    }
    __builtin_amdgcn_s_barrier();

    const char* _A = pR + wm * 4096;
    const char* _B = pR + 8192 + wn * 2048;
#pragma unroll
    for (int f = 0; f < 4; ++f)
      Ar[f] = *(const v4i*)(_A + f * 1024 + fr * 64 + u0);
#pragma unroll
    for (int g = 0; g < 2; ++g)
      Br[g] = *(const v4i*)(_B + g * 1024 + fr * 64 + u0);
#pragma unroll
    for (int f = 0; f < 4; ++f)
#pragma unroll
      for (int g = 0; g < 2; ++g)
        acc[f][g] = __builtin_amdgcn_mfma_i32_16x16x64_i8(Ar[f], Br[g], acc[f][g], 0, 0, 0);

    char* t = pR; pR = pS; pS = pF; pF = t;
  }
#undef STG
#undef VM

  // ------------- epilogue: block-cooperative wide-segment stores -----------
  __syncthreads();  // K-loop reads drained; repurpose lds[0..8448)

  float bdq[2];
#pragma unroll
  for (int g = 0; g < 2; ++g) bdq[g] = bdeq[Nbase + wn * 32 + g * 16 + fr];

  float* lws = (float*)lds;  // 16 rows x 132 f32 (stride 528B, 16B-aligned)

  const int srow2 = lane >> 5;        // 0..1
  const int sc4   = (lane & 31) * 4;  // 4-col group: 32 lanes cover 128 cols

#pragma unroll
  for (int p = 0; p < 8; ++p) {
    // writers: waves with wm == p>>2 scatter f = p&3 (16 rows x 128 cols)
    if (wm == (p >> 2)) {
      const int f = p & 3;
#pragma unroll
      for (int g = 0; g < 2; ++g)
#pragma unroll
        for (int i = 0; i < 4; ++i)
          lws[(q * 4 + i) * 132 + wn * 32 + g * 16 + fr] =
              (float)acc[f][g][i] * inv_denom + bdq[g];
    }
    __syncthreads();
    // all 8 waves: one v4f store instr = rows {2w, 2w+1}, 512B contiguous/row
    {
      const int r = (w << 1) | srow2;
      v4f v = *(const v4f*)&lws[r * 132 + sc4];
      *(v4f*)(out + (size_t)(Mbase + p * 16 + r) * N_OUT + Nbase + sc4) = v;  // plain cached store
    }
    __syncthreads();
  }
}

extern "C" void kernel_launch(void* const* d_in, const int* in_sizes, int n_in,
                              void* d_out, int out_size, void* d_ws, size_t ws_size,
                              hipStream_t stream) {
  const float* x = (const float*)d_in[0];
  const float* w = (const float*)d_in[1];
  const float* b = (const float*)d_in[2];
  float* out = (float*)d_out;

  char* ws = (char*)d_ws;
  float* amax = (float*)ws;                             // 3 floats
  float* bdeq = (float*)(ws + 256);                     // 4 KB
  float* px   = (float*)(ws + 8192);                    // 2048 partials
  float* pw   = (float*)(ws + 16384 + 8192);            // 256 partials
  signed char* qw = (signed char*)(ws + 65536);         // 1 MB
  signed char* qx = (signed char*)(ws + (1 << 21));     // 16 MB

  const int NPX = 2048, NPW = 256;
  hipLaunchKernelGGL(amax_both, dim3(NPX + NPW), dim3(256), 0, stream, x, w, px, pw);
  hipLaunchKernelGGL(quant_fin, dim3(NPX + NPW + 1), dim3(256), 0, stream,
                     x, w, b, qx, qw, px, pw, amax, bdeq);
  hipLaunchKernelGGL(gemm_kernel, dim3(128 * 8), dim3(512), 0, stream, qx, qw, amax, bdeq, out);
}

// Round 22
// 56.500 us; speedup vs baseline: 1.0332x; 1.0332x over previous
//
#include <hip/hip_runtime.h>

// AdaPT_Linear: per-tensor int8 quantized linear.
// out = (qx @ qw^T).f32 / (sa*sw) + qb.f32/sb
// x: [16384,1024] f32, w: [1024,1024] f32, b: [1024] f32, out: [16384,1024] f32
//
// FINAL CONFIG (R20, best measured 56.4us): 3 kernels —
//  K1 amax_both: two-tensor partial amax, 80%+ HBM.
//  K2 quant_fin: finalize folded in (every block redundantly reduces
//     partials -> bit-identical scales), quant x/w, bias block.
//  K3 gemm: 128x128/BK64/8-wave, triple-buffered single-barrier K-loop,
//     XOR-swizzle, block-cooperative wide-segment NONTEMPORAL stores
//     (A/B'd vs plain cached in R21: nt wins 56.4 vs 58.4).

#define M_ROWS 16384
#define K_DIM  1024
#define N_OUT  1024

typedef int v4i __attribute__((ext_vector_type(4)));
typedef float v4f __attribute__((ext_vector_type(4)));

__device__ __forceinline__ void gload_lds16(const void* g, void* l) {
  __builtin_amdgcn_global_load_lds(
      (const __attribute__((address_space(1))) void*)g,
      (__attribute__((address_space(3))) void*)l, 16, 0, 0);
}

__device__ __forceinline__ float block_reduce_max4(float m, float* red) {
#pragma unroll
  for (int off = 32; off > 0; off >>= 1)
    m = fmaxf(m, __shfl_down(m, off));
  const int wid = threadIdx.x >> 6, lane = threadIdx.x & 63;
  if (lane == 0) red[wid] = m;
  __syncthreads();
  float r = fmaxf(fmaxf(red[0], red[1]), fmaxf(red[2], red[3]));
  __syncthreads();
  return r;
}

// K1: blocks [0,2048) reduce x -> px, blocks [2048,2304) reduce w -> pw
__global__ void amax_both(const float* __restrict__ x, const float* __restrict__ wsrc,
                          float* __restrict__ px, float* __restrict__ pw) {
  __shared__ float red[4];
  const bool isx = blockIdx.x < 2048;
  const float* src = isx ? x : wsrc;
  const int n4   = isx ? (M_ROWS * K_DIM / 4) : (N_OUT * K_DIM / 4);
  const int nblk = isx ? 2048 : 256;
  const int bidl = isx ? blockIdx.x : blockIdx.x - 2048;
  float m = 0.0f;
  const int stride = nblk * 256;
  for (int idx = bidl * 256 + threadIdx.x; idx < n4; idx += stride) {
    float4 v = ((const float4*)src)[idx];
    m = fmaxf(m, fmaxf(fmaxf(fabsf(v.x), fabsf(v.y)), fmaxf(fabsf(v.z), fabsf(v.w))));
  }
  float r = block_reduce_max4(m, red);
  if (threadIdx.x == 0) (isx ? px : pw)[bidl] = r;
}

// K2: finalize folded into quant — EVERY block redundantly reduces the 2304
// partials (deterministic identical order -> bit-identical scales), then
// quantizes its slice. Block 2304 computes bias amax + bdeq + amax[].
__global__ void quant_fin(const float* __restrict__ x, const float* __restrict__ wsrc,
                          const float* __restrict__ bias,
                          signed char* __restrict__ qx, signed char* __restrict__ qw,
                          const float* __restrict__ px, const float* __restrict__ pw,
                          float* __restrict__ amax, float* __restrict__ bdeq) {
  __shared__ float red[4];
  const int tid = threadIdx.x;

  // local finalize (partials are >= 0; px: 512 float4, pw: 64 float4)
  float m = 0.0f;
#pragma unroll
  for (int i = 0; i < 2; ++i) {
    float4 v = ((const float4*)px)[tid + i * 256];
    m = fmaxf(m, fmaxf(fmaxf(v.x, v.y), fmaxf(v.z, v.w)));
  }
  float rx = block_reduce_max4(m, red);
  m = 0.0f;
  if (tid < 64) {
    float4 v = ((const float4*)pw)[tid];
    m = fmaxf(fmaxf(v.x, v.y), fmaxf(v.z, v.w));
  }
  float rw = block_reduce_max4(m, red);
  if (rx == 0.0f) rx = 1.0f;
  if (rw == 0.0f) rw = 1.0f;

  if (blockIdx.x == 2304) {  // bias block: amax[] + dequantized bias
    float4 bv = ((const float4*)bias)[tid];  // 256*4 == 1024
    m = fmaxf(fmaxf(fabsf(bv.x), fabsf(bv.y)), fmaxf(fabsf(bv.z), fabsf(bv.w)));
    float rb = block_reduce_max4(m, red);
    if (rb == 0.0f) rb = 1.0f;
    if (tid == 0) { amax[0] = rx; amax[1] = rw; amax[2] = rb; }
    const float sb = 127.0f / rb;
    float4 q;
    q.x = fminf(fmaxf(rintf(sb * bv.x), -127.0f), 127.0f) / sb;
    q.y = fminf(fmaxf(rintf(sb * bv.y), -127.0f), 127.0f) / sb;
    q.z = fminf(fmaxf(rintf(sb * bv.z), -127.0f), 127.0f) / sb;
    q.w = fminf(fmaxf(rintf(sb * bv.w), -127.0f), 127.0f) / sb;
    ((float4*)bdeq)[tid] = q;
    return;
  }

  const bool isx = blockIdx.x < 2048;
  const float* src = isx ? x : wsrc;
  signed char* dst = isx ? qx : qw;
  const int n4   = isx ? (M_ROWS * K_DIM / 4) : (N_OUT * K_DIM / 4);
  const int nblk = isx ? 2048 : 256;
  const int bidl = isx ? blockIdx.x : blockIdx.x - 2048;
  const float s = 127.0f / (isx ? rx : rw);
  const int stride = nblk * 256;
  for (int idx = bidl * 256 + tid; idx < n4; idx += stride) {
    float4 v = ((const float4*)src)[idx];
    int q0 = (int)fminf(fmaxf(rintf(s * v.x), -127.0f), 127.0f);
    int q1 = (int)fminf(fmaxf(rintf(s * v.y), -127.0f), 127.0f);
    int q2 = (int)fminf(fmaxf(rintf(s * v.z), -127.0f), 127.0f);
    int q3 = (int)fminf(fmaxf(rintf(s * v.w), -127.0f), 127.0f);
    unsigned int packed = (q0 & 0xff) | ((q1 & 0xff) << 8) |
                          ((q2 & 0xff) << 16) | ((q3 & 0xff) << 24);
    ((unsigned int*)dst)[idx] = packed;
  }
}

#define NKT 16

__global__ __launch_bounds__(512, 4) void gemm_kernel(
    const signed char* __restrict__ qx, const signed char* __restrict__ qw,
    const float* __restrict__ amax, const float* __restrict__ bdeq,
    float* __restrict__ out) {
  __shared__ char lds[49152];  // 3 bufs x 16KB (A 8K + B 8K)

  const int tid  = threadIdx.x;
  const int w    = tid >> 6;
  const int lane = tid & 63;
  const int wm = w >> 2;   // 0..1 (64 rows)
  const int wn = w & 3;    // 0..3 (32 cols)
  const int fr = lane & 15;
  const int q  = lane >> 4;

  // XCD-aware swizzle (grid 1024 = 8 XCDs x 128 contiguous)
  const int bid = blockIdx.x;
  const int wg  = (bid & 7) * 128 + (bid >> 3);
  const int Mbase = (wg >> 3) * 128;
  const int Nbase = (wg & 7) * 128;

  const signed char* gA = qx + (size_t)Mbase * K_DIM;
  const signed char* gB = qw + (size_t)Nbase * K_DIM;

  const int scol = ((tid & 3) ^ ((tid >> 3) & 3)) << 4;
  const size_t srowK = (size_t)(tid >> 2) * K_DIM;
  const int u0 = (q ^ ((fr >> 1) & 3)) << 4;

  const float inv_denom = (amax[0] * amax[1]) * (1.0f / 16129.0f);

  v4i acc[4][2] = {};
  v4i Ar[4], Br[2];

#define STG(BASE, T)                                                           \
  do {                                                                         \
    const int _k0 = (T)*64 + scol;                                             \
    gload_lds16(gA + srowK + _k0, (BASE) + tid * 16);                          \
    gload_lds16(gB + srowK + _k0, (BASE) + 8192 + tid * 16);                   \
  } while (0)

#define VM(N) asm volatile("s_waitcnt vmcnt(" #N ")" ::: "memory")

  char* pR = lds;
  char* pS = lds + 16384;
  char* pF = lds + 32768;

  STG(pR, 0);

#pragma unroll
  for (int kt = 0; kt < NKT; ++kt) {
    if (kt + 1 < NKT) {
      STG(pS, kt + 1);
      VM(2);
    } else {
      VM(0);
    }
    __builtin_amdgcn_s_barrier();

    const char* _A = pR + wm * 4096;
    const char* _B = pR + 8192 + wn * 2048;
#pragma unroll
    for (int f = 0; f < 4; ++f)
      Ar[f] = *(const v4i*)(_A + f * 1024 + fr * 64 + u0);
#pragma unroll
    for (int g = 0; g < 2; ++g)
      Br[g] = *(const v4i*)(_B + g * 1024 + fr * 64 + u0);
#pragma unroll
    for (int f = 0; f < 4; ++f)
#pragma unroll
      for (int g = 0; g < 2; ++g)
        acc[f][g] = __builtin_amdgcn_mfma_i32_16x16x64_i8(Ar[f], Br[g], acc[f][g], 0, 0, 0);

    char* t = pR; pR = pS; pS = pF; pF = t;
  }
#undef STG
#undef VM

  // ------------- epilogue: block-cooperative wide-segment stores -----------
  __syncthreads();  // K-loop reads drained; repurpose lds[0..8448)

  float bdq[2];
#pragma unroll
  for (int g = 0; g < 2; ++g) bdq[g] = bdeq[Nbase + wn * 32 + g * 16 + fr];

  float* lws = (float*)lds;  // 16 rows x 132 f32 (stride 528B, 16B-aligned)

  const int srow2 = lane >> 5;        // 0..1
  const int sc4   = (lane & 31) * 4;  // 4-col group: 32 lanes cover 128 cols

#pragma unroll
  for (int p = 0; p < 8; ++p) {
    // writers: waves with wm == p>>2 scatter f = p&3 (16 rows x 128 cols)
    if (wm == (p >> 2)) {
      const int f = p & 3;
#pragma unroll
      for (int g = 0; g < 2; ++g)
#pragma unroll
        for (int i = 0; i < 4; ++i)
          lws[(q * 4 + i) * 132 + wn * 32 + g * 16 + fr] =
              (float)acc[f][g][i] * inv_denom + bdq[g];
    }
    __syncthreads();
    // all 8 waves: one v4f store instr = rows {2w, 2w+1}, 512B contiguous/row
    {
      const int r = (w << 1) | srow2;
      v4f v = *(const v4f*)&lws[r * 132 + sc4];
      __builtin_nontemporal_store(
          v, (v4f*)(out + (size_t)(Mbase + p * 16 + r) * N_OUT + Nbase + sc4));
    }
    __syncthreads();
  }
}

extern "C" void kernel_launch(void* const* d_in, const int* in_sizes, int n_in,
                              void* d_out, int out_size, void* d_ws, size_t ws_size,
                              hipStream_t stream) {
  const float* x = (const float*)d_in[0];
  const float* w = (const float*)d_in[1];
  const float* b = (const float*)d_in[2];
  float* out = (float*)d_out;

  char* ws = (char*)d_ws;
  float* amax = (float*)ws;                             // 3 floats
  float* bdeq = (float*)(ws + 256);                     // 4 KB
  float* px   = (float*)(ws + 8192);                    // 2048 partials
  float* pw   = (float*)(ws + 16384 + 8192);            // 256 partials
  signed char* qw = (signed char*)(ws + 65536);         // 1 MB
  signed char* qx = (signed char*)(ws + (1 << 21));     // 16 MB

  const int NPX = 2048, NPW = 256;
  hipLaunchKernelGGL(amax_both, dim3(NPX + NPW), dim3(256), 0, stream, x, w, px, pw);
  hipLaunchKernelGGL(quant_fin, dim3(NPX + NPW + 1), dim3(256), 0, stream,
                     x, w, b, qx, qw, px, pw, amax, bdeq);
  hipLaunchKernelGGL(gemm_kernel, dim3(128 * 8), dim3(512), 0, stream, qx, qw, amax, bdeq, out);
}